// Round 4
// baseline (468.257 us; speedup 1.0000x reference)
//
#include <hip/hip_runtime.h>

namespace {

constexpr int NXc = 200, NYc = 200;
constexpr int NCELL = NXc * NYc;
constexpr int TSTEPS = 300;
constexpr int SRC_I = 30, SRC_J = 100;
constexpr int PNc = 20;
constexpr float Hc = 1.005f;         // DT*2.01

// ---- temporal blocking config ----
constexpr int T_SUB = 24;            // substeps per round (halo width)
constexpr int LT    = 64;
constexpr int VT    = LT - 2 * T_SUB;          // 16
constexpr int TI    = (NXc + VT - 1) / VT;     // 13
constexpr int TJ    = (NYc + VT - 1) / VT;     // 13
constexpr int NB    = TI * TJ;                 // 169 blocks
constexpr int NSTEP_TOT = TSTEPS - 1;          // 299
constexpr int NROUND    = (NSTEP_TOT + T_SUB - 1) / T_SUB; // 13
constexpr int GSTRIDE = 304;

constexpr int FLAG_STRIDE = 16;      // 64 B per flag -> no false sharing
constexpr int SYNC_WORDS  = NB * FLAG_STRIDE + 16;  // + gdone slot

// ---- probe owner constants ----
constexpr int PROBE_I = 170;
constexpr int PTX = PROBE_I / VT;
constexpr int PRr = PROBE_I - (PTX * VT - T_SUB);
static_assert(PRr >= T_SUB && PRr < T_SUB + VT, "");
constexpr int PW  = PRr >> 4;
constexpr int PCc = PRr & 15;

constexpr int PJ0 = 50, PJ1 = 100, PJ2 = 150;
constexpr int PTY0 = PJ0 / VT; constexpr int PCOL0 = PJ0 - (PTY0 * VT - T_SUB);
constexpr int PTY1 = PJ1 / VT; constexpr int PCOL1 = PJ1 - (PTY1 * VT - T_SUB);
constexpr int PTY2 = PJ2 / VT; constexpr int PCOL2 = PJ2 - (PTY2 * VT - T_SUB);
static_assert(PCOL0 >= T_SUB && PCOL0 < T_SUB + VT, "");
static_assert(PCOL1 >= T_SUB && PCOL1 < T_SUB + VT, "");
static_assert(PCOL2 >= T_SUB && PCOL2 < T_SUB + VT, "");
constexpr int PTID0 = (PW << 6) | PCOL0;
constexpr int PTID1 = (PW << 6) | PCOL1;
constexpr int PTID2 = (PW << 6) | PCOL2;

// probe L1 distances from source (g[p][t] == 0 exactly for t < PD[p])
constexpr int PD0 = 190, PD1 = 140, PD2 = 190;

} // namespace

// DPP whole-wave shifts; stencil consumes ev+wv symmetrically so the
// direction convention cannot change the sum; bound_ctrl zeros land in halo.
__device__ __forceinline__ float dpp_east(float v) {
    return __int_as_float(__builtin_amdgcn_update_dpp(
        0, __float_as_int(v), 0x130, 0xf, 0xf, true));
}
__device__ __forceinline__ float dpp_west(float v) {
    return __int_as_float(__builtin_amdgcn_update_dpp(
        0, __float_as_int(v), 0x138, 0xf, 0xf, true));
}

__global__ __launch_bounds__(256) void ws_init(unsigned* sync) {
    for (int i = threadIdx.x; i < SYNC_WORDS; i += 256) sync[i] = 0u;
}

// ---------------------------------------------------------------------------
// Neighbor-synced temporal-blocked FDTD (no global barrier):
//  - ready[bid] = rounds completed (store-only release; 64B-strided flags)
//  - before round l, active blocks wait for the 5x5 tile neighborhood
//    (halo 24 > VT 16 -> Chebyshev distance 2) to reach ready >= l
//  - light-cone-inactive blocks skip wait+reload+writeback and run ahead
//  - probe owners bump gdone after the last round; conv blocks (bid<8) wait
// ---------------------------------------------------------------------------
__global__ __launch_bounds__(256) void wave_coop(
    const float* __restrict__ x, const float* __restrict__ rho,
    float* __restrict__ out,
    float* __restrict__ a1, float* __restrict__ a2,
    float* __restrict__ b1, float* __restrict__ b2,
    float* __restrict__ g, unsigned* __restrict__ sync)
{
    const int bid  = blockIdx.x;          // 0..168
    const int tx   = bid / TJ;
    const int ty   = bid % TJ;
    const int tid  = threadIdx.x;
    const int lane = tid & 63;
    const int w    = tid >> 6;

    unsigned* ready = sync;
    unsigned* gdone = sync + NB * FLAG_STRIDE;

    const int i0 = tx * VT - T_SUB;
    const int j0 = ty * VT - T_SUB;
    const int gj = j0 + lane;
    const bool jin = (gj >= 0) && (gj < NYc);

    // dependency neighborhood (tiles whose interiors intersect my 64x64 load)
    const int axlo = (tx >= 2) ? tx - 2 : 0;
    const int axhi = (tx + 2 < TI) ? tx + 2 : TI - 1;
    const int aylo = (ty >= 2) ? ty - 2 : 0;
    const int ayhi = (ty + 2 < TJ) ? ty + 2 : TJ - 1;
    const int nay  = ayhi - aylo + 1;
    const int ndep = (axhi - axlo + 1) * nay;
    int mydep = -1;
    if (tid < ndep) {
        int ax = axlo + tid / nay;
        int ay = aylo + tid % nay;
        mydep = (ax * TJ + ay) * FLAG_STRIDE;
    }

    // light-cone distance of the loaded region from the source
    int di = i0 - SRC_I; if (di < 0) di = SRC_I - (i0 + LT - 1); if (di < 0) di = 0;
    int dj = j0 - SRC_J; if (dj < 0) dj = SRC_J - (j0 + LT - 1); if (dj < 0) dj = 0;
    const int Dtile = di + dj;

    // ---- coefficients (once, register-resident for all 299 steps) ----
    float Pr[16], Qr[16], Rr[16], y1r[16], y2r[16];
    #pragma unroll
    for (int c = 0; c < 16; ++c) {
        int gi = i0 + (w << 4) + c;
        bool in = jin && (gi >= 0) && (gi < NXc);
        float Pv = 0.f, Qv = 0.f, Rv = 0.f;
        if (in) {
            int idx = gi * NYc + gj;
            float r  = rho[idx];
            float rn = (gi > 0)       ? rho[idx - NYc] : 0.f;
            float rs = (gi < NXc - 1) ? rho[idx + NYc] : 0.f;
            float rw = (gj > 0)       ? rho[idx - 1]   : 0.f;
            float re = (gj < NYc - 1) ? rho[idx + 1]   : 0.f;
            float lp = 0.5f * r + 0.125f * (rn + rs + rw + re);

            float t_eta = tanhf(100.f * 0.5f);
            float denom = t_eta + tanhf(100.f * (1.f - 0.5f));
            float rho_p = (t_eta + tanhf(100.f * (lp - 0.5f))) / denom;
            float cc = 1.0f + (0.9f - 1.0f) * rho_p;
            float c2 = cc * cc;

            float ui = 0.f, uj = 0.f;
            if (gi <= PNc) ui = (float)(PNc - gi) * 0.05f;
            else if (gi >= NXc - PNc - 1) ui = (float)(gi - (NXc - PNc - 1)) * 0.05f;
            if (gj <= PNc) uj = (float)(PNc - gj) * 0.05f;
            else if (gj >= NYc - PNc - 1) uj = (float)(gj - (NYc - PNc - 1)) * 0.05f;
            float ui2 = ui * ui, uj2 = uj * uj;
            float bx = 3.0f * ui2 * ui2;
            float by = 3.0f * uj2 * uj2;
            float b  = sqrtf(bx * bx + by * by);

            float A = 1.0f / (4.0f + b);
            float h2inv = 1.0f / (Hc * Hc);
            Pv = A * (8.0f - 4.0f * c2 * h2inv);
            Qv = A * (4.0f - b);
            Rv = A * c2 * h2inv;
        }
        Pr[c] = Pv; Qr[c] = Qv; Rr[c] = Rv;
        y1r[c] = (jin && (i0 + (w << 4) + c) == SRC_I && gj == SRC_J) ? 1.0f : 0.f;
        y2r[c] = 0.f;
    }

    const bool pb0 = (tx == PTX && ty == PTY0 && tid == PTID0);
    const bool pb1 = (tx == PTX && ty == PTY1 && tid == PTID1);
    const bool pb2 = (tx == PTX && ty == PTY2 && tid == PTID2);

    __shared__ float topSh[2][4][64];
    __shared__ float botSh[2][4][64];

    int s0 = 0;
    for (int l = 0; l < NROUND; ++l) {
        int ns = NSTEP_TOT - s0; if (ns > T_SUB) ns = T_SUB;
        const bool active = (Dtile <= s0 + ns);

        if (active) {
            if (l > 0) {
                // wait for 5x5 neighborhood to finish round l-1 (ready >= l)
                if (mydep >= 0) {
                    unsigned tgt = (unsigned)l;
                    while (__hip_atomic_load(&ready[mydep], __ATOMIC_RELAXED,
                                             __HIP_MEMORY_SCOPE_AGENT) < tgt)
                        __builtin_amdgcn_s_sleep(1);
                }
                __syncthreads();
                __threadfence();   // acquire: invalidate stale halo lines

                const float* s1 = (l & 1) ? b1 : a1;
                const float* s2 = (l & 1) ? b2 : a2;
                #pragma unroll
                for (int c = 0; c < 16; ++c) {
                    int gi = i0 + (w << 4) + c;
                    bool in = jin && (gi >= 0) && (gi < NXc);
                    int gidx = gi * NYc + gj;
                    y1r[c] = in ? s1[gidx] : 0.f;
                    y2r[c] = in ? s2[gidx] : 0.f;
                }
            }

            for (int k = 0; k < ns; ++k) {
                int p = k & 1;
                topSh[p][w][lane] = y1r[0];
                botSh[p][w][lane] = y1r[15];
                __syncthreads();
                float nTop = (w > 0) ? botSh[p][w - 1][lane] : 0.f;
                float sBot = (w < 3) ? topSh[p][w + 1][lane] : 0.f;
                // single barrier: next substep writes the other buffer and is
                // unreachable until all waves pass this barrier

                float yn[16];
                #pragma unroll
                for (int c = 0; c < 16; ++c) {
                    float nv = (c == 0)  ? nTop : y1r[c - 1];
                    float sv = (c == 15) ? sBot : y1r[c + 1];
                    float ev = dpp_east(y1r[c]);
                    float wv = dpp_west(y1r[c]);
                    yn[c] = Pr[c] * y1r[c] - Qr[c] * y2r[c] + Rr[c] * ((nv + sv) + (ev + wv));
                }
                #pragma unroll
                for (int c = 0; c < 16; ++c) { y2r[c] = y1r[c]; y1r[c] = yn[c]; }

                int t = s0 + k + 1;
                if (pb0) g[0 * GSTRIDE + t] = y1r[PCc];
                if (pb1) g[1 * GSTRIDE + t] = y1r[PCc];
                if (pb2) g[2 * GSTRIDE + t] = y1r[PCc];
            }
        } else {
            // field identically zero here all round; probe owners record zeros
            if (pb0) for (int k = 0; k < ns; ++k) g[0 * GSTRIDE + s0 + k + 1] = 0.f;
            if (pb1) for (int k = 0; k < ns; ++k) g[1 * GSTRIDE + s0 + k + 1] = 0.f;
            if (pb2) for (int k = 0; k < ns; ++k) g[2 * GSTRIDE + s0 + k + 1] = 0.f;
        }

        // writeback valid interior. Inactive blocks only need rounds 0,1 (both
        // buffer sets then hold durable zeros under their interior; activity is
        // monotone, so skipped rounds leave zeros in place — exact).
        if (l < NROUND - 1 && (active || l < 2)) {
            float* d1 = (l & 1) ? a1 : b1;
            float* d2 = (l & 1) ? a2 : b2;
            #pragma unroll
            for (int c = 0; c < 16; ++c) {
                int r = (w << 4) + c;
                int gi = i0 + r;
                if (r >= T_SUB && r < T_SUB + VT &&
                    lane >= T_SUB && lane < T_SUB + VT &&
                    gi >= 0 && gi < NXc && gj >= 0 && gj < NYc) {
                    int gidx = gi * NYc + gj;
                    d1[gidx] = y1r[c];
                    d2[gidx] = y2r[c];
                }
            }
        }

        // release: flush my stores, then publish round completion (store-only)
        if (active || l < 2) __threadfence();
        __syncthreads();
        if (tid == 0)
            __hip_atomic_store(&ready[bid * FLAG_STRIDE], (unsigned)(l + 1),
                               __ATOMIC_RELAXED, __HIP_MEMORY_SCOPE_AGENT);
        s0 += ns;
    }

    // ---- g handoff: probe owners -> conv blocks ----
    const bool owner_blk = (tx == PTX) && (ty == PTY0 || ty == PTY1 || ty == PTY2);
    if (owner_blk) {
        // last round's release fence already flushed all g stores
        if (tid == 0) atomicAdd(gdone, 1u);
    }

    // ---- convolution + intensity + normalize (blocks 0..7, one per batch) ----
    if (bid < 8) {
        if (tid == 0) {
            while (__hip_atomic_load(gdone, __ATOMIC_RELAXED,
                                     __HIP_MEMORY_SCOPE_AGENT) < 3u)
                __builtin_amdgcn_s_sleep(1);
        }
        __syncthreads();
        __threadfence();

        __shared__ float xs[304];
        __shared__ float gsm[3][304];
        __shared__ float red[3][4];

        for (int idx = tid; idx < TSTEPS; idx += 256) {
            xs[idx]     = x[bid * TSTEPS + idx];
            gsm[0][idx] = idx ? g[0 * GSTRIDE + idx] : 0.f;   // g[p][0] == 0
            gsm[1][idx] = idx ? g[1 * GSTRIDE + idx] : 0.f;
            gsm[2][idx] = idx ? g[2 * GSTRIDE + idx] : 0.f;
        }
        __syncthreads();

        float acc0 = 0.f, acc1 = 0.f, acc2 = 0.f;
        for (int t = tid; t < TSTEPS; t += 256) {
            float c0 = 0.f, c1 = 0.f, c2 = 0.f;
            int m1 = t - PD1;
            for (int s = 0; s <= m1; ++s) c1 += xs[s] * gsm[1][t - s];
            int m0 = t - PD0;   // PD0 == PD2
            for (int s = 0; s <= m0; ++s) {
                float xv = xs[s];
                c0 += xv * gsm[0][t - s];
                c2 += xv * gsm[2][t - s];
            }
            acc0 += c0 * c0; acc1 += c1 * c1; acc2 += c2 * c2;
        }

        float accs[3] = {acc0, acc1, acc2};
        #pragma unroll
        for (int p = 0; p < 3; ++p) {
            float v = accs[p];
            #pragma unroll
            for (int off = 32; off > 0; off >>= 1) v += __shfl_down(v, off, 64);
            if ((tid & 63) == 0) red[p][tid >> 6] = v;
        }
        __syncthreads();
        if (tid == 0) {
            float I0 = red[0][0] + red[0][1] + red[0][2] + red[0][3];
            float I1 = red[1][0] + red[1][1] + red[1][2] + red[1][3];
            float I2 = red[2][0] + red[2][1] + red[2][2] + red[2][3];
            float inv = 1.0f / (I0 + I1 + I2);
            out[bid * 3 + 0] = I0 * inv;
            out[bid * 3 + 1] = I1 * inv;
            out[bid * 3 + 2] = I2 * inv;
        }
    }
}

// ---------------------------------------------------------------------------
extern "C" void kernel_launch(void* const* d_in, const int* in_sizes, int n_in,
                              void* d_out, int out_size, void* d_ws, size_t ws_size,
                              hipStream_t stream)
{
    const float* x   = (const float*)d_in[0];   // (8, 300)
    const float* rho = (const float*)d_in[1];   // (200, 200)
    float* out = (float*)d_out;                 // (8, 3) float32

    float* base = (float*)d_ws;
    float* a1 = base;
    float* a2 = a1 + NCELL;
    float* b1 = a2 + NCELL;
    float* b2 = b1 + NCELL;
    float* g  = b2 + NCELL;                     // 3 * GSTRIDE
    unsigned* sync = (unsigned*)(g + 3 * GSTRIDE);

    ws_init<<<1, 256, 0, stream>>>(sync);

    void* args[] = { (void*)&x, (void*)&rho, (void*)&out,
                     (void*)&a1, (void*)&a2, (void*)&b1, (void*)&b2,
                     (void*)&g, (void*)&sync };
    hipLaunchCooperativeKernel((const void*)wave_coop, dim3(NB), dim3(256),
                               args, 0, stream);
}

// Round 5
// 235.184 us; speedup vs baseline: 1.9910x; 1.9910x over previous
//
#include <hip/hip_runtime.h>

namespace {

constexpr int NXc = 200, NYc = 200;
constexpr int NCELL = NXc * NYc;
constexpr int TSTEPS = 300;
constexpr int SRC_I = 30, SRC_J = 100;
constexpr int PNc = 20;
constexpr float Hc = 1.005f;         // DT*2.01

// ---- temporal blocking config ----
constexpr int T_SUB = 24;            // substeps per round (halo width)
constexpr int LT    = 64;
constexpr int VT    = LT - 2 * T_SUB;          // 16
constexpr int TI    = (NXc + VT - 1) / VT;     // 13
constexpr int TJ    = (NYc + VT - 1) / VT;     // 13
constexpr int NB    = TI * TJ;                 // 169 blocks
constexpr int NSTEP_TOT = TSTEPS - 1;          // 299
constexpr int NROUND    = (NSTEP_TOT + T_SUB - 1) / T_SUB; // 13
constexpr int GSTRIDE = 304;

constexpr int FLAG_STRIDE = 16;      // 64 B per flag line
constexpr int GO_SLOT     = NB * FLAG_STRIDE;
constexpr int SYNC_WORDS  = NB * FLAG_STRIDE + 16;
constexpr int GATHER      = NB - 1;  // corner tile: light-cone-idle until round 8

// ---- probe owner constants ----
constexpr int PROBE_I = 170;
constexpr int PTX = PROBE_I / VT;
constexpr int PRr = PROBE_I - (PTX * VT - T_SUB);
static_assert(PRr >= T_SUB && PRr < T_SUB + VT, "");
constexpr int PW  = PRr >> 4;
constexpr int PCc = PRr & 15;

constexpr int PJ0 = 50, PJ1 = 100, PJ2 = 150;
constexpr int PTY0 = PJ0 / VT; constexpr int PCOL0 = PJ0 - (PTY0 * VT - T_SUB);
constexpr int PTY1 = PJ1 / VT; constexpr int PCOL1 = PJ1 - (PTY1 * VT - T_SUB);
constexpr int PTY2 = PJ2 / VT; constexpr int PCOL2 = PJ2 - (PTY2 * VT - T_SUB);
static_assert(PCOL0 >= T_SUB && PCOL0 < T_SUB + VT, "");
static_assert(PCOL1 >= T_SUB && PCOL1 < T_SUB + VT, "");
static_assert(PCOL2 >= T_SUB && PCOL2 < T_SUB + VT, "");
constexpr int PTID0 = (PW << 6) | PCOL0;
constexpr int PTID1 = (PW << 6) | PCOL1;
constexpr int PTID2 = (PW << 6) | PCOL2;

// probe L1 distances from source (g[p][t] == 0 exactly for t < PD[p])
constexpr int PD0 = 190, PD1 = 140, PD2 = 190;

} // namespace

// device-scope (MALL-coherent, L1/L2-bypassing) accessors — no fences needed
__device__ __forceinline__ float dev_ld(const float* p) {
    return __hip_atomic_load(p, __ATOMIC_RELAXED, __HIP_MEMORY_SCOPE_AGENT);
}
__device__ __forceinline__ void dev_st(float* p, float v) {
    __hip_atomic_store(p, v, __ATOMIC_RELAXED, __HIP_MEMORY_SCOPE_AGENT);
}
__device__ __forceinline__ unsigned dev_ldu(const unsigned* p) {
    return __hip_atomic_load(p, __ATOMIC_RELAXED, __HIP_MEMORY_SCOPE_AGENT);
}
__device__ __forceinline__ void dev_stu(unsigned* p, unsigned v) {
    __hip_atomic_store(p, v, __ATOMIC_RELAXED, __HIP_MEMORY_SCOPE_AGENT);
}

// DPP whole-wave shifts; stencil consumes ev+wv symmetrically so the
// direction convention cannot change the sum; bound_ctrl zeros land in halo.
__device__ __forceinline__ float dpp_east(float v) {
    return __int_as_float(__builtin_amdgcn_update_dpp(
        0, __float_as_int(v), 0x130, 0xf, 0xf, true));
}
__device__ __forceinline__ float dpp_west(float v) {
    return __int_as_float(__builtin_amdgcn_update_dpp(
        0, __float_as_int(v), 0x138, 0xf, 0xf, true));
}

__global__ __launch_bounds__(256) void ws_init(unsigned* sync) {
    for (int i = threadIdx.x; i < SYNC_WORDS; i += 256) sync[i] = 0u;
}

// ---------------------------------------------------------------------------
// Temporal-blocked FDTD with a fence-free flag barrier:
//  - ALL cross-block data (y buffers, g, flags) moves via device-scope (sc1)
//    loads/stores -> MALL-coherent; no __threadfence / L2 writeback anywhere
//  - release = s_waitcnt vmcnt(0) + arrive[bid] store; gatherer block polls
//    all 169 arrive lines in parallel, publishes go; others poll go
//  - light-cone-inactive blocks skip reload/substeps; probe owners record
//    zeros; conv blocks (bid<8) run after the final go
// ---------------------------------------------------------------------------
__global__ __launch_bounds__(256) void wave_coop(
    const float* __restrict__ x, const float* __restrict__ rho,
    float* __restrict__ out,
    float* __restrict__ a1, float* __restrict__ a2,
    float* __restrict__ b1, float* __restrict__ b2,
    float* __restrict__ g, unsigned* __restrict__ sync)
{
    const int bid  = blockIdx.x;          // 0..168
    const int tx   = bid / TJ;
    const int ty   = bid % TJ;
    const int tid  = threadIdx.x;
    const int lane = tid & 63;
    const int w    = tid >> 6;

    unsigned* gop = sync + GO_SLOT;

    const int i0 = tx * VT - T_SUB;
    const int j0 = ty * VT - T_SUB;
    const int gj = j0 + lane;
    const bool jin = (gj >= 0) && (gj < NYc);

    // light-cone distance of the loaded region from the source
    int di = i0 - SRC_I; if (di < 0) di = SRC_I - (i0 + LT - 1); if (di < 0) di = 0;
    int dj = j0 - SRC_J; if (dj < 0) dj = SRC_J - (j0 + LT - 1); if (dj < 0) dj = 0;
    const int Dtile = di + dj;

    // ---- coefficients (once, register-resident for all 299 steps) ----
    float Pr[16], Qr[16], Rr[16], y1r[16], y2r[16];
    #pragma unroll
    for (int c = 0; c < 16; ++c) {
        int gi = i0 + (w << 4) + c;
        bool in = jin && (gi >= 0) && (gi < NXc);
        float Pv = 0.f, Qv = 0.f, Rv = 0.f;
        if (in) {
            int idx = gi * NYc + gj;
            float r  = rho[idx];
            float rn = (gi > 0)       ? rho[idx - NYc] : 0.f;
            float rs = (gi < NXc - 1) ? rho[idx + NYc] : 0.f;
            float rw = (gj > 0)       ? rho[idx - 1]   : 0.f;
            float re = (gj < NYc - 1) ? rho[idx + 1]   : 0.f;
            float lp = 0.5f * r + 0.125f * (rn + rs + rw + re);

            float t_eta = tanhf(100.f * 0.5f);
            float denom = t_eta + tanhf(100.f * (1.f - 0.5f));
            float rho_p = (t_eta + tanhf(100.f * (lp - 0.5f))) / denom;
            float cc = 1.0f + (0.9f - 1.0f) * rho_p;
            float c2 = cc * cc;

            float ui = 0.f, uj = 0.f;
            if (gi <= PNc) ui = (float)(PNc - gi) * 0.05f;
            else if (gi >= NXc - PNc - 1) ui = (float)(gi - (NXc - PNc - 1)) * 0.05f;
            if (gj <= PNc) uj = (float)(PNc - gj) * 0.05f;
            else if (gj >= NYc - PNc - 1) uj = (float)(gj - (NYc - PNc - 1)) * 0.05f;
            float ui2 = ui * ui, uj2 = uj * uj;
            float bx = 3.0f * ui2 * ui2;
            float by = 3.0f * uj2 * uj2;
            float b  = sqrtf(bx * bx + by * by);

            float A = 1.0f / (4.0f + b);
            float h2inv = 1.0f / (Hc * Hc);
            Pv = A * (8.0f - 4.0f * c2 * h2inv);
            Qv = A * (4.0f - b);
            Rv = A * c2 * h2inv;
        }
        Pr[c] = Pv; Qr[c] = Qv; Rr[c] = Rv;
        y1r[c] = (jin && (i0 + (w << 4) + c) == SRC_I && gj == SRC_J) ? 1.0f : 0.f;
        y2r[c] = 0.f;
    }

    const bool pb0 = (tx == PTX && ty == PTY0 && tid == PTID0);
    const bool pb1 = (tx == PTX && ty == PTY1 && tid == PTID1);
    const bool pb2 = (tx == PTX && ty == PTY2 && tid == PTID2);

    __shared__ float topSh[2][4][64];
    __shared__ float botSh[2][4][64];

    int s0 = 0;
    for (int l = 0; l < NROUND; ++l) {
        int ns = NSTEP_TOT - s0; if (ns > T_SUB) ns = T_SUB;
        const bool active = (Dtile <= s0 + ns);

        if (active) {
            if (l > 0) {
                // acquire: wait for round-l go (gatherer already gathered it)
                if (bid != GATHER && tid == 0) {
                    unsigned tgt = (unsigned)l;
                    while (dev_ldu(gop) < tgt) __builtin_amdgcn_s_sleep(1);
                }
                __syncthreads();

                const float* s1 = (l & 1) ? b1 : a1;
                const float* s2 = (l & 1) ? b2 : a2;
                #pragma unroll
                for (int c = 0; c < 16; ++c) {
                    int gi = i0 + (w << 4) + c;
                    bool in = jin && (gi >= 0) && (gi < NXc);
                    int gidx = gi * NYc + gj;
                    y1r[c] = in ? dev_ld(&s1[gidx]) : 0.f;
                    y2r[c] = in ? dev_ld(&s2[gidx]) : 0.f;
                }
            }

            for (int k = 0; k < ns; ++k) {
                int p = k & 1;
                topSh[p][w][lane] = y1r[0];
                botSh[p][w][lane] = y1r[15];
                __syncthreads();
                float nTop = (w > 0) ? botSh[p][w - 1][lane] : 0.f;
                float sBot = (w < 3) ? topSh[p][w + 1][lane] : 0.f;
                // single barrier: next substep writes the other buffer and is
                // unreachable until all waves pass this barrier

                float yn[16];
                #pragma unroll
                for (int c = 0; c < 16; ++c) {
                    float nv = (c == 0)  ? nTop : y1r[c - 1];
                    float sv = (c == 15) ? sBot : y1r[c + 1];
                    float ev = dpp_east(y1r[c]);
                    float wv = dpp_west(y1r[c]);
                    yn[c] = Pr[c] * y1r[c] - Qr[c] * y2r[c] + Rr[c] * ((nv + sv) + (ev + wv));
                }
                #pragma unroll
                for (int c = 0; c < 16; ++c) { y2r[c] = y1r[c]; y1r[c] = yn[c]; }

                int t = s0 + k + 1;
                if (pb0) dev_st(&g[0 * GSTRIDE + t], y1r[PCc]);
                if (pb1) dev_st(&g[1 * GSTRIDE + t], y1r[PCc]);
                if (pb2) dev_st(&g[2 * GSTRIDE + t], y1r[PCc]);
            }
        } else {
            // field identically zero here all round; probe owners record zeros
            if (pb0) for (int k = 0; k < ns; ++k) dev_st(&g[0 * GSTRIDE + s0 + k + 1], 0.f);
            if (pb1) for (int k = 0; k < ns; ++k) dev_st(&g[1 * GSTRIDE + s0 + k + 1], 0.f);
            if (pb2) for (int k = 0; k < ns; ++k) dev_st(&g[2 * GSTRIDE + s0 + k + 1], 0.f);
        }

        // writeback valid interior (inactive: only rounds 0,1 — durable zeros;
        // activity is monotone so later skipped rounds leave zeros — exact)
        if (l < NROUND - 1 && (active || l < 2)) {
            float* d1 = (l & 1) ? a1 : b1;
            float* d2 = (l & 1) ? a2 : b2;
            #pragma unroll
            for (int c = 0; c < 16; ++c) {
                int r = (w << 4) + c;
                int gi = i0 + r;
                if (r >= T_SUB && r < T_SUB + VT &&
                    lane >= T_SUB && lane < T_SUB + VT &&
                    gi >= 0 && gi < NXc && gj >= 0 && gj < NYc) {
                    int gidx = gi * NYc + gj;
                    dev_st(&d1[gidx], y1r[c]);
                    dev_st(&d2[gidx], y2r[c]);
                }
            }
        }

        // release: drain my device-scope stores, then publish arrival
        asm volatile("s_waitcnt vmcnt(0)" ::: "memory");
        __syncthreads();
        if (tid == 0)
            dev_stu(&sync[bid * FLAG_STRIDE], (unsigned)(l + 1));

        // gatherer: wait for all 169 arrivals (parallel, one line per thread),
        // then publish go = l+1 (its own next-round reload needs no go-poll)
        if (bid == GATHER) {
            if (tid < NB) {
                unsigned tgt = (unsigned)(l + 1);
                while (dev_ldu(&sync[tid * FLAG_STRIDE]) < tgt)
                    __builtin_amdgcn_s_sleep(1);
            }
            __syncthreads();
            if (tid == 0) dev_stu(gop, (unsigned)(l + 1));
        }
        s0 += ns;
    }

    // ---- convolution + intensity + normalize (blocks 0..7, one per batch) ----
    if (bid < 8) {
        if (tid == 0) {
            while (dev_ldu(gop) < (unsigned)NROUND) __builtin_amdgcn_s_sleep(1);
        }
        __syncthreads();

        __shared__ float xs[304];
        __shared__ float gsm[3][304];
        __shared__ float red[3][4];

        for (int idx = tid; idx < TSTEPS; idx += 256) {
            xs[idx]     = x[bid * TSTEPS + idx];
            gsm[0][idx] = idx ? dev_ld(&g[0 * GSTRIDE + idx]) : 0.f;  // g[p][0]==0
            gsm[1][idx] = idx ? dev_ld(&g[1 * GSTRIDE + idx]) : 0.f;
            gsm[2][idx] = idx ? dev_ld(&g[2 * GSTRIDE + idx]) : 0.f;
        }
        __syncthreads();

        float acc0 = 0.f, acc1 = 0.f, acc2 = 0.f;
        for (int t = tid; t < TSTEPS; t += 256) {
            float c0 = 0.f, c1 = 0.f, c2 = 0.f;
            int m1 = t - PD1;
            for (int s = 0; s <= m1; ++s) c1 += xs[s] * gsm[1][t - s];
            int m0 = t - PD0;   // PD0 == PD2
            for (int s = 0; s <= m0; ++s) {
                float xv = xs[s];
                c0 += xv * gsm[0][t - s];
                c2 += xv * gsm[2][t - s];
            }
            acc0 += c0 * c0; acc1 += c1 * c1; acc2 += c2 * c2;
        }

        float accs[3] = {acc0, acc1, acc2};
        #pragma unroll
        for (int p = 0; p < 3; ++p) {
            float v = accs[p];
            #pragma unroll
            for (int off = 32; off > 0; off >>= 1) v += __shfl_down(v, off, 64);
            if ((tid & 63) == 0) red[p][tid >> 6] = v;
        }
        __syncthreads();
        if (tid == 0) {
            float I0 = red[0][0] + red[0][1] + red[0][2] + red[0][3];
            float I1 = red[1][0] + red[1][1] + red[1][2] + red[1][3];
            float I2 = red[2][0] + red[2][1] + red[2][2] + red[2][3];
            float inv = 1.0f / (I0 + I1 + I2);
            out[bid * 3 + 0] = I0 * inv;
            out[bid * 3 + 1] = I1 * inv;
            out[bid * 3 + 2] = I2 * inv;
        }
    }
}

// ---------------------------------------------------------------------------
extern "C" void kernel_launch(void* const* d_in, const int* in_sizes, int n_in,
                              void* d_out, int out_size, void* d_ws, size_t ws_size,
                              hipStream_t stream)
{
    const float* x   = (const float*)d_in[0];   // (8, 300)
    const float* rho = (const float*)d_in[1];   // (200, 200)
    float* out = (float*)d_out;                 // (8, 3) float32

    float* base = (float*)d_ws;
    float* a1 = base;
    float* a2 = a1 + NCELL;
    float* b1 = a2 + NCELL;
    float* b2 = b1 + NCELL;
    float* g  = b2 + NCELL;                     // 3 * GSTRIDE
    unsigned* sync = (unsigned*)(g + 3 * GSTRIDE);

    ws_init<<<1, 256, 0, stream>>>(sync);

    void* args[] = { (void*)&x, (void*)&rho, (void*)&out,
                     (void*)&a1, (void*)&a2, (void*)&b1, (void*)&b2,
                     (void*)&g, (void*)&sync };
    hipLaunchCooperativeKernel((const void*)wave_coop, dim3(NB), dim3(256),
                               args, 0, stream);
}

// Round 6
// 177.888 us; speedup vs baseline: 2.6323x; 1.3221x over previous
//
#include <hip/hip_runtime.h>

namespace {

constexpr int NXc = 200, NYc = 200;
constexpr int NCELL = NXc * NYc;
constexpr int TSTEPS = 300;
constexpr int SRC_I = 30, SRC_J = 100;
constexpr int PNc = 20;
constexpr float Hc = 1.005f;         // DT*2.01

// ---- temporal blocking config ----
constexpr int T_SUB = 24;            // substeps per round (halo width)
constexpr int LT    = 64;
constexpr int VT    = LT - 2 * T_SUB;          // 16
constexpr int TI    = (NXc + VT - 1) / VT;     // 13
constexpr int TJ    = (NYc + VT - 1) / VT;     // 13
constexpr int NB    = TI * TJ;                 // 169 blocks
constexpr int NSTEP_TOT = TSTEPS - 1;          // 299
constexpr int NROUND    = (NSTEP_TOT + T_SUB - 1) / T_SUB; // 13
constexpr int GSTRIDE = 304;

constexpr int MBW = 32;              // mailbox words per block (128 B, 2 lines)
constexpr int GD_SLOT = NB * MBW;    // 3 gdone slots after mailboxes
constexpr int SYNC_WORDS = NB * MBW + 16;

// ---- probe owner constants ----
constexpr int PROBE_I = 170;
constexpr int PTX = PROBE_I / VT;
constexpr int PRr = PROBE_I - (PTX * VT - T_SUB);
static_assert(PRr >= T_SUB && PRr < T_SUB + VT, "");
constexpr int PW  = PRr >> 4;
constexpr int PCc = PRr & 15;

constexpr int PJ0 = 50, PJ1 = 100, PJ2 = 150;
constexpr int PTY0 = PJ0 / VT; constexpr int PCOL0 = PJ0 - (PTY0 * VT - T_SUB);
constexpr int PTY1 = PJ1 / VT; constexpr int PCOL1 = PJ1 - (PTY1 * VT - T_SUB);
constexpr int PTY2 = PJ2 / VT; constexpr int PCOL2 = PJ2 - (PTY2 * VT - T_SUB);
static_assert(PCOL0 >= T_SUB && PCOL0 < T_SUB + VT, "");
static_assert(PCOL1 >= T_SUB && PCOL1 < T_SUB + VT, "");
static_assert(PCOL2 >= T_SUB && PCOL2 < T_SUB + VT, "");
constexpr int PTID0 = (PW << 6) | PCOL0;
constexpr int PTID1 = (PW << 6) | PCOL1;
constexpr int PTID2 = (PW << 6) | PCOL2;

// probe L1 distances from source (g[p][t] == 0 exactly for t < PD[p])
constexpr int PD0 = 190, PD1 = 140, PD2 = 190;

} // namespace

// device-scope (MALL-coherent, L1/L2-bypassing) accessors — no cache fences
__device__ __forceinline__ float dev_ld(const float* p) {
    return __hip_atomic_load(p, __ATOMIC_RELAXED, __HIP_MEMORY_SCOPE_AGENT);
}
__device__ __forceinline__ void dev_st(float* p, float v) {
    __hip_atomic_store(p, v, __ATOMIC_RELAXED, __HIP_MEMORY_SCOPE_AGENT);
}
__device__ __forceinline__ unsigned dev_ldu(const unsigned* p) {
    return __hip_atomic_load(p, __ATOMIC_RELAXED, __HIP_MEMORY_SCOPE_AGENT);
}
__device__ __forceinline__ void dev_stu(unsigned* p, unsigned v) {
    __hip_atomic_store(p, v, __ATOMIC_RELAXED, __HIP_MEMORY_SCOPE_AGENT);
}

// DPP whole-wave shifts; stencil consumes ev+wv symmetrically so the
// direction convention cannot change the sum; bound_ctrl zeros land in halo.
__device__ __forceinline__ float dpp_east(float v) {
    return __int_as_float(__builtin_amdgcn_update_dpp(
        0, __float_as_int(v), 0x130, 0xf, 0xf, true));
}
__device__ __forceinline__ float dpp_west(float v) {
    return __int_as_float(__builtin_amdgcn_update_dpp(
        0, __float_as_int(v), 0x138, 0xf, 0xf, true));
}

__global__ __launch_bounds__(256) void ws_init(unsigned* sync) {
    for (int i = threadIdx.x; i < SYNC_WORDS; i += 256) sync[i] = 0u;
}

// ---------------------------------------------------------------------------
// Temporal-blocked FDTD with single-hop mailbox neighbor sync (fence-free):
//  - all cross-block data via device-scope (MALL-coherent) loads/stores
//  - end of round l: per-wave vmcnt(0) drain, __syncthreads, then 25 lanes
//    push l+1 into the 5x5 neighbors' mailboxes (slot 24-tid in their frame)
//  - top of round l: 25 lanes poll OWN mailbox (2 contiguous cachelines);
//    skew between neighbors <= 1 round; ping-pong WAR-safe
//  - step computes into the y2 array (no register copy); k unrolled in pairs
// ---------------------------------------------------------------------------
__global__ __launch_bounds__(256) void wave_coop(
    const float* __restrict__ x, const float* __restrict__ rho,
    float* __restrict__ out,
    float* __restrict__ a1, float* __restrict__ a2,
    float* __restrict__ b1, float* __restrict__ b2,
    float* __restrict__ g, unsigned* __restrict__ sync)
{
    const int bid  = blockIdx.x;          // 0..168
    const int tx   = bid / TJ;
    const int ty   = bid % TJ;
    const int tid  = threadIdx.x;
    const int lane = tid & 63;
    const int w    = tid >> 6;

    unsigned* mb    = sync;               // NB * MBW
    unsigned* gdone = sync + GD_SLOT;     // 3 slots

    const int i0 = tx * VT - T_SUB;
    const int j0 = ty * VT - T_SUB;
    const int gj = j0 + lane;
    const bool jin = (gj >= 0) && (gj < NYc);

    // mailbox endpoints for this thread (tid < 25 -> neighbor (dx,dy))
    bool nb_valid = false;
    unsigned* recv_p = nullptr;
    unsigned* send_p = nullptr;
    if (tid < 25) {
        int dx = tid / 5 - 2, dy = tid % 5 - 2;
        int nx = tx + dx, ny = ty + dy;
        nb_valid = (nx >= 0 && nx < TI && ny >= 0 && ny < TJ);
        if (nb_valid) {
            recv_p = &mb[bid * MBW + tid];
            send_p = &mb[(nx * TJ + ny) * MBW + (24 - tid)];
        }
    }

    // light-cone distance of the loaded region from the source
    int di = i0 - SRC_I; if (di < 0) di = SRC_I - (i0 + LT - 1); if (di < 0) di = 0;
    int dj = j0 - SRC_J; if (dj < 0) dj = SRC_J - (j0 + LT - 1); if (dj < 0) dj = 0;
    const int Dtile = di + dj;

    // ---- coefficients (once, register-resident for all 299 steps) ----
    float Pr[16], Qr[16], Rr[16], y1r[16], y2r[16];
    #pragma unroll
    for (int c = 0; c < 16; ++c) {
        int gi = i0 + (w << 4) + c;
        bool in = jin && (gi >= 0) && (gi < NXc);
        float Pv = 0.f, Qv = 0.f, Rv = 0.f;
        if (in) {
            int idx = gi * NYc + gj;
            float r  = rho[idx];
            float rn = (gi > 0)       ? rho[idx - NYc] : 0.f;
            float rs = (gi < NXc - 1) ? rho[idx + NYc] : 0.f;
            float rw = (gj > 0)       ? rho[idx - 1]   : 0.f;
            float re = (gj < NYc - 1) ? rho[idx + 1]   : 0.f;
            float lp = 0.5f * r + 0.125f * (rn + rs + rw + re);

            float t_eta = tanhf(100.f * 0.5f);
            float denom = t_eta + tanhf(100.f * (1.f - 0.5f));
            float rho_p = (t_eta + tanhf(100.f * (lp - 0.5f))) / denom;
            float cc = 1.0f + (0.9f - 1.0f) * rho_p;
            float c2 = cc * cc;

            float ui = 0.f, uj = 0.f;
            if (gi <= PNc) ui = (float)(PNc - gi) * 0.05f;
            else if (gi >= NXc - PNc - 1) ui = (float)(gi - (NXc - PNc - 1)) * 0.05f;
            if (gj <= PNc) uj = (float)(PNc - gj) * 0.05f;
            else if (gj >= NYc - PNc - 1) uj = (float)(gj - (NYc - PNc - 1)) * 0.05f;
            float ui2 = ui * ui, uj2 = uj * uj;
            float bx = 3.0f * ui2 * ui2;
            float by = 3.0f * uj2 * uj2;
            float b  = sqrtf(bx * bx + by * by);

            float A = 1.0f / (4.0f + b);
            float h2inv = 1.0f / (Hc * Hc);
            Pv = A * (8.0f - 4.0f * c2 * h2inv);
            Qv = A * (4.0f - b);
            Rv = A * c2 * h2inv;
        }
        Pr[c] = Pv; Qr[c] = Qv; Rr[c] = Rv;
        y1r[c] = (jin && (i0 + (w << 4) + c) == SRC_I && gj == SRC_J) ? 1.0f : 0.f;
        y2r[c] = 0.f;
    }

    const bool pb0 = (tx == PTX && ty == PTY0 && tid == PTID0);
    const bool pb1 = (tx == PTX && ty == PTY1 && tid == PTID1);
    const bool pb2 = (tx == PTX && ty == PTY2 && tid == PTID2);

    __shared__ float topSh[2][4][64];
    __shared__ float botSh[2][4][64];

    // one substep: OUT <- P*CUR - Q*OUT + R*lap(CUR); OUT becomes newest
    #define STEP(CUR, OUT, kk, tt) do {                                        \
        int p_ = (kk) & 1;                                                     \
        topSh[p_][w][lane] = CUR[0];                                           \
        botSh[p_][w][lane] = CUR[15];                                          \
        __syncthreads();                                                       \
        float nTop_ = (w > 0) ? botSh[p_][w - 1][lane] : 0.f;                  \
        float sBot_ = (w < 3) ? topSh[p_][w + 1][lane] : 0.f;                  \
        _Pragma("unroll")                                                      \
        for (int c = 0; c < 16; ++c) {                                         \
            float nv = (c == 0)  ? nTop_ : CUR[c - 1];                         \
            float sv = (c == 15) ? sBot_ : CUR[c + 1];                         \
            float ev = dpp_east(CUR[c]);                                       \
            float wv = dpp_west(CUR[c]);                                       \
            OUT[c] = Pr[c] * CUR[c] - Qr[c] * OUT[c]                           \
                   + Rr[c] * ((nv + sv) + (ev + wv));                          \
        }                                                                      \
        if (pb0) dev_st(&g[0 * GSTRIDE + (tt)], OUT[PCc]);                     \
        if (pb1) dev_st(&g[1 * GSTRIDE + (tt)], OUT[PCc]);                     \
        if (pb2) dev_st(&g[2 * GSTRIDE + (tt)], OUT[PCc]);                     \
    } while (0)

    int s0 = 0;
    for (int l = 0; l < NROUND; ++l) {
        int ns = NSTEP_TOT - s0; if (ns > T_SUB) ns = T_SUB;
        const bool active = (Dtile <= s0 + ns);

        if (active) {
            if (l > 0) {
                // wait: all 5x5 neighbors finished round l-1 (own mailbox >= l)
                if (nb_valid) {
                    unsigned tgt = (unsigned)l;
                    while (dev_ldu(recv_p) < tgt) __builtin_amdgcn_s_sleep(1);
                }
                __syncthreads();

                const float* s1 = (l & 1) ? b1 : a1;
                const float* s2 = (l & 1) ? b2 : a2;
                #pragma unroll
                for (int c = 0; c < 16; ++c) {
                    int gi = i0 + (w << 4) + c;
                    bool in = jin && (gi >= 0) && (gi < NXc);
                    int gidx = gi * NYc + gj;
                    y1r[c] = in ? dev_ld(&s1[gidx]) : 0.f;
                    y2r[c] = in ? dev_ld(&s2[gidx]) : 0.f;
                }
            }

            // substeps, unrolled in role-swapping pairs (no register copies)
            int k = 0;
            for (; k + 1 < ns; k += 2) {
                STEP(y1r, y2r, k,     s0 + k + 1);
                STEP(y2r, y1r, k + 1, s0 + k + 2);
            }
            if (k < ns) {
                // odd tail only in the final round (ns=11), where writeback is
                // skipped — newest ends in y2r, only probe stores matter
                STEP(y1r, y2r, k, s0 + k + 1);
            }
        } else {
            // field identically zero here all round; probe owners record zeros
            if (pb0) for (int k = 0; k < ns; ++k) dev_st(&g[0 * GSTRIDE + s0 + k + 1], 0.f);
            if (pb1) for (int k = 0; k < ns; ++k) dev_st(&g[1 * GSTRIDE + s0 + k + 1], 0.f);
            if (pb2) for (int k = 0; k < ns; ++k) dev_st(&g[2 * GSTRIDE + s0 + k + 1], 0.f);
        }

        // writeback valid interior (inactive: only rounds 0,1 — durable zeros;
        // activity is monotone so later skipped rounds leave zeros — exact).
        // After even ns, newest is y1r, previous y2r (roles restored).
        if (l < NROUND - 1 && (active || l < 2)) {
            float* d1 = (l & 1) ? a1 : b1;
            float* d2 = (l & 1) ? a2 : b2;
            #pragma unroll
            for (int c = 0; c < 16; ++c) {
                int r = (w << 4) + c;
                int gi = i0 + r;
                if (r >= T_SUB && r < T_SUB + VT &&
                    lane >= T_SUB && lane < T_SUB + VT &&
                    gi >= 0 && gi < NXc && gj >= 0 && gj < NYc) {
                    int gidx = gi * NYc + gj;
                    dev_st(&d1[gidx], y1r[c]);
                    dev_st(&d2[gidx], y2r[c]);
                }
            }
        }

        // release: per-wave drain, block-wide rendezvous, push to neighbors
        asm volatile("s_waitcnt vmcnt(0)" ::: "memory");
        __syncthreads();
        if (nb_valid) dev_stu(send_p, (unsigned)(l + 1));
        s0 += ns;
    }

    // ---- g handoff: probe-owner blocks -> conv blocks (store-only slots) ----
    if (tid == 0) {
        if (tx == PTX && ty == PTY0) dev_stu(&gdone[0], 1u);
        if (tx == PTX && ty == PTY1) dev_stu(&gdone[1], 1u);
        if (tx == PTX && ty == PTY2) dev_stu(&gdone[2], 1u);
    }

    // ---- convolution + intensity + normalize (blocks 0..7, one per batch) ----
    if (bid < 8) {
        if (tid < 3) {
            while (dev_ldu(&gdone[tid]) < 1u) __builtin_amdgcn_s_sleep(1);
        }
        __syncthreads();

        __shared__ float xs[304];
        __shared__ float gsm[3][304];
        __shared__ float red[3][4];

        for (int idx = tid; idx < TSTEPS; idx += 256) {
            xs[idx]     = x[bid * TSTEPS + idx];
            gsm[0][idx] = idx ? dev_ld(&g[0 * GSTRIDE + idx]) : 0.f;  // g[p][0]==0
            gsm[1][idx] = idx ? dev_ld(&g[1 * GSTRIDE + idx]) : 0.f;
            gsm[2][idx] = idx ? dev_ld(&g[2 * GSTRIDE + idx]) : 0.f;
        }
        __syncthreads();

        float acc0 = 0.f, acc1 = 0.f, acc2 = 0.f;
        for (int t = tid; t < TSTEPS; t += 256) {
            float c0 = 0.f, c1 = 0.f, c2 = 0.f;
            int m1 = t - PD1;
            for (int s = 0; s <= m1; ++s) c1 += xs[s] * gsm[1][t - s];
            int m0 = t - PD0;   // PD0 == PD2
            for (int s = 0; s <= m0; ++s) {
                float xv = xs[s];
                c0 += xv * gsm[0][t - s];
                c2 += xv * gsm[2][t - s];
            }
            acc0 += c0 * c0; acc1 += c1 * c1; acc2 += c2 * c2;
        }

        float accs[3] = {acc0, acc1, acc2};
        #pragma unroll
        for (int p = 0; p < 3; ++p) {
            float v = accs[p];
            #pragma unroll
            for (int off = 32; off > 0; off >>= 1) v += __shfl_down(v, off, 64);
            if ((tid & 63) == 0) red[p][tid >> 6] = v;
        }
        __syncthreads();
        if (tid == 0) {
            float I0 = red[0][0] + red[0][1] + red[0][2] + red[0][3];
            float I1 = red[1][0] + red[1][1] + red[1][2] + red[1][3];
            float I2 = red[2][0] + red[2][1] + red[2][2] + red[2][3];
            float inv = 1.0f / (I0 + I1 + I2);
            out[bid * 3 + 0] = I0 * inv;
            out[bid * 3 + 1] = I1 * inv;
            out[bid * 3 + 2] = I2 * inv;
        }
    }
    #undef STEP
}

// ---------------------------------------------------------------------------
extern "C" void kernel_launch(void* const* d_in, const int* in_sizes, int n_in,
                              void* d_out, int out_size, void* d_ws, size_t ws_size,
                              hipStream_t stream)
{
    const float* x   = (const float*)d_in[0];   // (8, 300)
    const float* rho = (const float*)d_in[1];   // (200, 200)
    float* out = (float*)d_out;                 // (8, 3) float32

    float* base = (float*)d_ws;
    float* a1 = base;
    float* a2 = a1 + NCELL;
    float* b1 = a2 + NCELL;
    float* b2 = b1 + NCELL;
    float* g  = b2 + NCELL;                     // 3 * GSTRIDE
    unsigned* sync = (unsigned*)(g + 3 * GSTRIDE);

    ws_init<<<1, 256, 0, stream>>>(sync);

    void* args[] = { (void*)&x, (void*)&rho, (void*)&out,
                     (void*)&a1, (void*)&a2, (void*)&b1, (void*)&b2,
                     (void*)&g, (void*)&sync };
    hipLaunchCooperativeKernel((const void*)wave_coop, dim3(NB), dim3(256),
                               args, 0, stream);
}